// Round 10
// baseline (196.720 us; speedup 1.0000x reference)
//
#include <hip/hip_runtime.h>
#include <hip/hip_bf16.h>
#include <math.h>

#define INV_T (1.0f / 0.07f)

typedef __bf16 bf16x8 __attribute__((ext_vector_type(8)));
typedef float f32x4 __attribute__((ext_vector_type(4)));

__device__ __forceinline__ void gld16(const void* g, void* l) {
    __builtin_amdgcn_global_load_lds(
        (const __attribute__((address_space(1))) unsigned int*)g,
        (__attribute__((address_space(3))) unsigned int*)l,
        16, 0, 0);
}

// relaxed agent-scope atomic load: pipelined coherent read (not an RMW)
__device__ __forceinline__ float agent_load(const float* p) {
    return __hip_atomic_load(p, __ATOMIC_RELAXED, __HIP_MEMORY_SCOPE_AGENT);
}

// ---------------- normalize + bf16 pack + positive dot + S-zero ------------
__global__ __launch_bounds__(256) void norm_kernel(
    const float4* __restrict__ f1, const float4* __restrict__ f2,
    ushort4* __restrict__ F, float* __restrict__ S, float* __restrict__ P,
    int* __restrict__ cnt, int B) {
    const int i = blockIdx.x;
    const int t = threadIdx.x;

    float4 x = f1[i * 256 + t];
    float4 y = f2[i * 256 + t];

    float s1 = x.x * x.x + x.y * x.y + x.z * x.z + x.w * x.w;
    float s2 = y.x * y.x + y.y * y.y + y.z * y.z + y.w * y.w;
    float dd = x.x * y.x + x.y * y.y + x.z * y.z + x.w * y.w;

    for (int o = 32; o > 0; o >>= 1) {
        s1 += __shfl_down(s1, o);
        s2 += __shfl_down(s2, o);
        dd += __shfl_down(dd, o);
    }
    __shared__ float red[4][3];
    const int wv = t >> 6, ln = t & 63;
    if (ln == 0) { red[wv][0] = s1; red[wv][1] = s2; red[wv][2] = dd; }
    __syncthreads();
    s1 = red[0][0] + red[1][0] + red[2][0] + red[3][0];
    s2 = red[0][1] + red[1][1] + red[2][1] + red[3][1];
    dd = red[0][2] + red[1][2] + red[2][2] + red[3][2];

    const float rn1 = 1.0f / fmaxf(sqrtf(s1), 1e-12f);
    const float rn2 = 1.0f / fmaxf(sqrtf(s2), 1e-12f);

    union { ushort4 u; __hip_bfloat16 h[4]; } p;
    p.h[0] = __float2bfloat16(x.x * rn1);
    p.h[1] = __float2bfloat16(x.y * rn1);
    p.h[2] = __float2bfloat16(x.z * rn1);
    p.h[3] = __float2bfloat16(x.w * rn1);
    F[(size_t)i * 256 + t] = p.u;
    p.h[0] = __float2bfloat16(y.x * rn2);
    p.h[1] = __float2bfloat16(y.y * rn2);
    p.h[2] = __float2bfloat16(y.z * rn2);
    p.h[3] = __float2bfloat16(y.w * rn2);
    F[(size_t)(B + i) * 256 + t] = p.u;

    if (t == 0) {
        P[i] = dd * rn1 * rn2;
        S[i] = 0.0f;
        S[B + i] = 0.0f;
        if (i == 0) { cnt[0] = 0; cnt[1] = 0; }   // steal ctr, done ctr
    }
}

// ---------------- fused sim-GEMM + exp + row/col-sum (upper triangle) ------
// 128x128 tiles, PERSISTENT work-stealing, grid = 1024 (= measured 4/CU
// residency; R9 showed 5/CU at 32KB LDS does NOT fit: 5*32768 = exactly
// 160KiB and the CU reserves some LDS).
// Job order = CHEAP JOBS LAST (greedy-stealing makespan = last-job start +
// duration): 2016 strict-upper tiles (tii<tjj) first, then 64 diagonal
// tiles (tii==tjj) at ~0.6 cost each:
//   - B-staging skipped (A==B; B-fragments read from As)     [-4 gld16/kb]
//   - wave(1,0): all output masked -> skip MFMA entirely
//   - waves(0,0),(1,1): only mi<=ni MFMAs (10/16); mi>ni is all gRow>gCol
// Skipped MFMAs leave acc=0; the unchanged epilogue masks those entries
// anyway (gRow>=gCol -> 0), so correctness is structural.
// Makespan model: t=1: steal 992 fulls + 32 diags; t~1.6: diag-finishers
// take last 32 diags -> ~2.2 rounds (was 3.0).
// NOTE: keep __launch_bounds__(256,2) — R4: min-waves=3 capped VGPR at 84
// and spilled the accumulator (188 MB scratch WRITE).
__global__ __launch_bounds__(256, 2) void sim_kernel(
    const __hip_bfloat16* __restrict__ F, float* __restrict__ S,
    const float* __restrict__ P, float* __restrict__ out,
    int* __restrict__ cnt, int N, int B, int D, int noff, int ntiles) {
    // exactly 32 KB; control vars alias the tile buffer (barrier-separated)
    __shared__ __align__(16) __hip_bfloat16 smem[16384];
    __hip_bfloat16 (*As)[64] = (__hip_bfloat16(*)[64])smem;
    __hip_bfloat16 (*Bs)[64] = (__hip_bfloat16(*)[64])(smem + 8192);
    int* kSh = (int*)smem;
    int* lastF = ((int*)smem) + 1;
    float (*redf)[2] = (float(*)[2])(smem + 16);

    const int tid  = threadIdx.x;
    const int wave = tid >> 6;
    const int lane = tid & 63;
    const int quad = lane >> 4;
    const int l16  = lane & 15;

    const int srow   = lane >> 3;                 // 0..7
    const int ldsOff = (lane & 7) * 8;            // dest slot (elements)
    const int srcOff = ((lane & 7) ^ srow) * 8;   // swizzled global chunk

    const int waveRow = (wave >> 1) * 64;
    const int waveCol = (wave & 1) * 64;
    const int swz = l16 & 7;

    for (;;) {
        if (tid == 0) *kSh = atomicAdd(&cnt[0], 1);
        __syncthreads();
        const int k = *kSh;
        __syncthreads();   // all threads read k BEFORE staging overwrites it
        if (k >= ntiles) break;

        int tii, tjj;
        if (k < noff) {
            // strict-upper enum: k = tjj*(tjj-1)/2 + tii, tii < tjj
            tjj = (int)((1.0f + sqrtf(8.0f * (float)k + 1.0f)) * 0.5f);
            while (tjj * (tjj - 1) / 2 > k) --tjj;
            while ((tjj + 1) * tjj / 2 <= k) ++tjj;
            tii = k - tjj * (tjj - 1) / 2;
        } else {
            tii = tjj = k - noff;   // diagonal tiles LAST (cheap jobs last)
        }
        const bool isDiag = (tii == tjj);
        const int bRow = tii * 128;
        const int bCol = tjj * 128;

        // wave-uniform MFMA role for this tile:
        const bool fullMfma = !isDiag || (wave == 1);   // off-diag quadrant
        const bool skipMfma = isDiag && (wave == 2);    // fully-masked quad

        f32x4 acc[4][4];
#pragma unroll
        for (int mi = 0; mi < 4; ++mi)
#pragma unroll
            for (int ni = 0; ni < 4; ++ni)
                acc[mi][ni] = (f32x4){0.0f, 0.0f, 0.0f, 0.0f};

        const __hip_bfloat16 (*Bsrc)[64] =
            isDiag ? (const __hip_bfloat16(*)[64])As
                   : (const __hip_bfloat16(*)[64])Bs;

        for (int kb = 0; kb < D; kb += 64) {
#pragma unroll
            for (int p = 0; p < 4; ++p) {
                const int rowT = (p * 4 + wave) * 8 + srow;   // 0..127
                gld16(&F[(size_t)(bRow + rowT) * D + kb + srcOff], &As[rowT][ldsOff]);
            }
            if (!isDiag) {
#pragma unroll
                for (int p = 0; p < 4; ++p) {
                    const int rowT = (p * 4 + wave) * 8 + srow;   // 0..127
                    gld16(&F[(size_t)(bCol + rowT) * D + kb + srcOff], &Bs[rowT][ldsOff]);
                }
            }
            __syncthreads();

            if (!skipMfma) {
#pragma unroll
                for (int ks = 0; ks < 2; ++ks) {
                    const int slot = ((ks * 4 + quad) ^ swz) * 8;
                    bf16x8 bf[4];
#pragma unroll
                    for (int ni = 0; ni < 4; ++ni)
                        bf[ni] = *(const bf16x8*)&Bsrc[waveCol + ni * 16 + l16][slot];
                    if (fullMfma) {
#pragma unroll
                        for (int mi = 0; mi < 4; ++mi) {
                            const bf16x8 af = *(const bf16x8*)&As[waveRow + mi * 16 + l16][slot];
#pragma unroll
                            for (int ni = 0; ni < 4; ++ni)
                                acc[mi][ni] = __builtin_amdgcn_mfma_f32_16x16x32_bf16(
                                    af, bf[ni], acc[mi][ni], 0, 0, 0);
                        }
                    } else {
                        // diag quadrant: only mi<=ni (mi>ni is all gRow>gCol)
#pragma unroll
                        for (int mi = 0; mi < 4; ++mi) {
                            const bf16x8 af = *(const bf16x8*)&As[waveRow + mi * 16 + l16][slot];
#pragma unroll
                            for (int ni = 0; ni < 4; ++ni)
                                if (ni >= mi)
                                    acc[mi][ni] = __builtin_amdgcn_mfma_f32_16x16x32_bf16(
                                        af, bf[ni], acc[mi][ni], 0, 0, 0);
                        }
                    }
                }
            }
            __syncthreads();
        }

        // epilogue: e = (gRow<gCol) ? exp((c-1)/T) : 0; row+col sums.
        // (safe with zero accs from skipped MFMAs: those are gRow>=gCol.)
        if (!skipMfma) {
#pragma unroll
            for (int mi = 0; mi < 4; ++mi)
#pragma unroll
                for (int ni = 0; ni < 4; ++ni)
#pragma unroll
                    for (int r = 0; r < 4; ++r) {
                        const int gRow = bRow + waveRow + mi * 16 + quad * 4 + r;
                        const int gCol = bCol + waveCol + ni * 16 + l16;
                        acc[mi][ni][r] = (gRow < gCol)
                            ? __expf((acc[mi][ni][r] - 1.0f) * INV_T) : 0.0f;
                    }

            // row sums: reduce over l16 (col dimension)
#pragma unroll
            for (int mi = 0; mi < 4; ++mi)
#pragma unroll
                for (int r = 0; r < 4; ++r) {
                    const int gRow = bRow + waveRow + mi * 16 + quad * 4 + r;
                    float v = acc[mi][0][r] + acc[mi][1][r] + acc[mi][2][r] + acc[mi][3][r];
                    v += __shfl_xor(v, 1);
                    v += __shfl_xor(v, 2);
                    v += __shfl_xor(v, 4);
                    v += __shfl_xor(v, 8);
                    if (l16 == 0) atomicAdd(&S[gRow], v);
                }

            // col sums: reduce over quad (row dimension)
#pragma unroll
            for (int ni = 0; ni < 4; ++ni) {
                float cv = 0.0f;
#pragma unroll
                for (int mi = 0; mi < 4; ++mi)
#pragma unroll
                    for (int r = 0; r < 4; ++r) cv += acc[mi][ni][r];
                cv += __shfl_xor(cv, 16);
                cv += __shfl_xor(cv, 32);
                if (quad == 0) atomicAdd(&S[bCol + waveCol + ni * 16 + l16], cv);
            }
        }
    }

    // ---- last-done-block finalize (R5/R7-proven) ----
    asm volatile("s_waitcnt vmcnt(0) lgkmcnt(0)" ::: "memory");
    if (tid == 0) *lastF = (atomicAdd(&cnt[1], 1) == (int)gridDim.x - 1);
    __syncthreads();
    if (!*lastF) return;

    float s0 = 0.0f, s1 = 0.0f, s2 = 0.0f, s3 = 0.0f;
    for (int i = tid; i < N; i += 1024) {      // N=8192: 8 iters x 4 loads
        const float a = agent_load(&S[i]);
        const float b = agent_load(&S[i + 256]);
        const float c = agent_load(&S[i + 512]);
        const float d = agent_load(&S[i + 768]);
        s0 += __logf(a); s1 += __logf(b); s2 += __logf(c); s3 += __logf(d);
    }
    float s = (s0 + s1) + (s2 + s3);

    float pp = 0.0f;
    for (int i = tid; i < B; i += 1024)        // B=4096: 4 iters x 4 loads
        pp += P[i] + P[i + 256] + P[i + 512] + P[i + 768];

    for (int o = 32; o > 0; o >>= 1) {
        s += __shfl_down(s, o);
        pp += __shfl_down(pp, o);
    }
    if (lane == 0) { redf[wave][0] = s; redf[wave][1] = pp; }
    __syncthreads();
    if (tid == 0) {
        const float sl = redf[0][0] + redf[1][0] + redf[2][0] + redf[3][0];
        const float ps = redf[0][1] + redf[1][1] + redf[2][1] + redf[3][1];
        out[0] = INV_T + sl / (float)N - ps * (2.0f * INV_T / (float)N);
    }
}

extern "C" void kernel_launch(void* const* d_in, const int* in_sizes, int n_in,
                              void* d_out, int out_size, void* d_ws, size_t ws_size,
                              hipStream_t stream) {
    const int D = 1024;
    const int B = in_sizes[0] / D;       // 4096
    const int N = 2 * B;                 // 8192
    const int M = N / 128;               // 64 tile rows/cols
    const int noff = M * (M - 1) / 2;    // 2016 strict-upper tiles
    const int ntiles = noff + M;         // + 64 diagonal tiles = 2080
    const int nblocks = 1024;            // persistent: 4/CU (measured cap)

    const float* f1 = (const float*)d_in[0];
    const float* f2 = (const float*)d_in[1];

    __hip_bfloat16* F = (__hip_bfloat16*)d_ws;  // N*D bf16 = 16 MB
    float* S = (float*)((char*)d_ws + (size_t)N * D * sizeof(__hip_bfloat16));
    float* P = S + N;                // B floats
    int* cnt = (int*)(P + B);        // [0]=steal ctr, [1]=done ctr

    norm_kernel<<<dim3(B), dim3(256), 0, stream>>>(
        (const float4*)f1, (const float4*)f2, (ushort4*)F, S, P, cnt, B);
    sim_kernel<<<dim3(nblocks), dim3(256), 0, stream>>>(
        F, S, P, (float*)d_out, cnt, N, B, D, noff, ntiles);
}

// Round 11
// 172.552 us; speedup vs baseline: 1.1401x; 1.1401x over previous
//
#include <hip/hip_runtime.h>
#include <hip/hip_bf16.h>
#include <math.h>

#define INV_T (1.0f / 0.07f)

typedef __bf16 bf16x8 __attribute__((ext_vector_type(8)));
typedef float f32x4 __attribute__((ext_vector_type(4)));

__device__ __forceinline__ void gld16(const void* g, void* l) {
    __builtin_amdgcn_global_load_lds(
        (const __attribute__((address_space(1))) unsigned int*)g,
        (__attribute__((address_space(3))) unsigned int*)l,
        16, 0, 0);
}

// relaxed agent-scope atomic load: pipelined coherent read (not an RMW)
__device__ __forceinline__ float agent_load(const float* p) {
    return __hip_atomic_load(p, __ATOMIC_RELAXED, __HIP_MEMORY_SCOPE_AGENT);
}

// ---------------- normalize + bf16 pack + positive dot + S-zero ------------
// one block per pair-row i; also zeroes S[i], S[B+i]; P[i] = cos(f1_i,f2_i)
__global__ __launch_bounds__(256) void norm_kernel(
    const float4* __restrict__ f1, const float4* __restrict__ f2,
    ushort4* __restrict__ F, float* __restrict__ S, float* __restrict__ P,
    int* __restrict__ cnt, int B) {
    const int i = blockIdx.x;
    const int t = threadIdx.x;

    float4 x = f1[i * 256 + t];
    float4 y = f2[i * 256 + t];

    float s1 = x.x * x.x + x.y * x.y + x.z * x.z + x.w * x.w;
    float s2 = y.x * y.x + y.y * y.y + y.z * y.z + y.w * y.w;
    float dd = x.x * y.x + x.y * y.y + x.z * y.z + x.w * y.w;

    for (int o = 32; o > 0; o >>= 1) {
        s1 += __shfl_down(s1, o);
        s2 += __shfl_down(s2, o);
        dd += __shfl_down(dd, o);
    }
    __shared__ float red[4][3];
    const int wv = t >> 6, ln = t & 63;
    if (ln == 0) { red[wv][0] = s1; red[wv][1] = s2; red[wv][2] = dd; }
    __syncthreads();
    s1 = red[0][0] + red[1][0] + red[2][0] + red[3][0];
    s2 = red[0][1] + red[1][1] + red[2][1] + red[3][1];
    dd = red[0][2] + red[1][2] + red[2][2] + red[3][2];

    const float rn1 = 1.0f / fmaxf(sqrtf(s1), 1e-12f);
    const float rn2 = 1.0f / fmaxf(sqrtf(s2), 1e-12f);

    union { ushort4 u; __hip_bfloat16 h[4]; } p;
    p.h[0] = __float2bfloat16(x.x * rn1);
    p.h[1] = __float2bfloat16(x.y * rn1);
    p.h[2] = __float2bfloat16(x.z * rn1);
    p.h[3] = __float2bfloat16(x.w * rn1);
    F[(size_t)i * 256 + t] = p.u;
    p.h[0] = __float2bfloat16(y.x * rn2);
    p.h[1] = __float2bfloat16(y.y * rn2);
    p.h[2] = __float2bfloat16(y.z * rn2);
    p.h[3] = __float2bfloat16(y.w * rn2);
    F[(size_t)(B + i) * 256 + t] = p.u;

    if (t == 0) {
        P[i] = dd * rn1 * rn2;
        S[i] = 0.0f;
        S[B + i] = 0.0f;
        if (i == 0) { cnt[0] = 0; cnt[1] = 0; }
    }
}

// ---------------- fused sim-GEMM + exp + row/col-sum (upper triangle) ------
// 128x256 block tile (rows ti*128, cols tj*256), tiles with ti <= 2*tj+1.
// Rule: count ONLY strictly-upper elements (gRow < gCol); credit exp to both
// S[gRow] and S[gCol]. Each unordered pair is computed exactly once; diagonal
// excluded automatically. 4 waves in 2x2, each wave 64x128 (4x8 of 16x16x32).
// XOR-swizzled LDS: chunk slot s at row r holds global chunk s^(r&7).
// Last-finishing block runs the finalize with PIPELINED relaxed agent loads.
// HOT LOOP IS BRANCH-FREE (R10: in-loop wave-role masking bloated VGPR
// 64->88 and cost 35%). Keep __launch_bounds__(256,2) (R4: min-waves=3
// capped VGPR at 84 -> 188 MB scratch spill).
__global__ __launch_bounds__(256, 2) void sim_kernel(
    const __hip_bfloat16* __restrict__ F, float* __restrict__ S,
    const float* __restrict__ P, float* __restrict__ out,
    int* __restrict__ cnt, int N, int B, int D) {
    __shared__ __align__(16) __hip_bfloat16 As[128][64];  // 16 KB
    __shared__ __align__(16) __hip_bfloat16 Bs[256][64];  // 32 KB

    // ---- decode linear block id -> (ti, tj): k = tj^2 + tj + ti ----
    const int k = blockIdx.x;
    int tj = (int)((sqrtf(4.0f * (float)k + 1.0f) - 1.0f) * 0.5f);
    while ((tj + 1) * (tj + 2) <= k) ++tj;
    while (tj * (tj + 1) > k) --tj;
    const int ti = k - tj * (tj + 1);  // in [0, 2*tj+2)
    const int bRow = ti * 128;
    const int bCol = tj * 256;

    const int tid  = threadIdx.x;
    const int wave = tid >> 6;
    const int lane = tid & 63;
    const int quad = lane >> 4;
    const int l16  = lane & 15;

    const int srow   = lane >> 3;                 // 0..7
    const int ldsOff = (lane & 7) * 8;            // dest slot (elements)
    const int srcOff = ((lane & 7) ^ srow) * 8;   // swizzled global chunk

    const int waveRow = (wave >> 1) * 64;
    const int waveCol = (wave & 1) * 128;
    const int swz = l16 & 7;

    f32x4 acc[4][8];
#pragma unroll
    for (int mi = 0; mi < 4; ++mi)
#pragma unroll
        for (int ni = 0; ni < 8; ++ni)
            acc[mi][ni] = (f32x4){0.0f, 0.0f, 0.0f, 0.0f};

    for (int kb = 0; kb < D; kb += 64) {
#pragma unroll
        for (int p = 0; p < 4; ++p) {
            const int rowT = (p * 4 + wave) * 8 + srow;   // 0..127
            gld16(&F[(size_t)(bRow + rowT) * D + kb + srcOff], &As[rowT][ldsOff]);
        }
#pragma unroll
        for (int p = 0; p < 8; ++p) {
            const int rowT = (p * 4 + wave) * 8 + srow;   // 0..255
            gld16(&F[(size_t)(bCol + rowT) * D + kb + srcOff], &Bs[rowT][ldsOff]);
        }
        __syncthreads();

#pragma unroll
        for (int ks = 0; ks < 2; ++ks) {
            const int slot = ((ks * 4 + quad) ^ swz) * 8;
            bf16x8 bf[8];
#pragma unroll
            for (int ni = 0; ni < 8; ++ni)
                bf[ni] = *(const bf16x8*)&Bs[waveCol + ni * 16 + l16][slot];
#pragma unroll
            for (int mi = 0; mi < 4; ++mi) {
                const bf16x8 af = *(const bf16x8*)&As[waveRow + mi * 16 + l16][slot];
#pragma unroll
                for (int ni = 0; ni < 8; ++ni)
                    acc[mi][ni] = __builtin_amdgcn_mfma_f32_16x16x32_bf16(
                        af, bf[ni], acc[mi][ni], 0, 0, 0);
            }
        }
        __syncthreads();
    }

    // ---- epilogue: e = (gRow<gCol) ? exp((c-1)/T) : 0; row+col sums ----
#pragma unroll
    for (int mi = 0; mi < 4; ++mi)
#pragma unroll
        for (int ni = 0; ni < 8; ++ni)
#pragma unroll
            for (int r = 0; r < 4; ++r) {
                const int gRow = bRow + waveRow + mi * 16 + quad * 4 + r;
                const int gCol = bCol + waveCol + ni * 16 + l16;
                acc[mi][ni][r] = (gRow < gCol)
                    ? __expf((acc[mi][ni][r] - 1.0f) * INV_T) : 0.0f;
            }

    // row sums
#pragma unroll
    for (int mi = 0; mi < 4; ++mi)
#pragma unroll
        for (int r = 0; r < 4; ++r) {
            const int gRow = bRow + waveRow + mi * 16 + quad * 4 + r;
            float v = 0.0f;
#pragma unroll
            for (int ni = 0; ni < 8; ++ni) v += acc[mi][ni][r];
            v += __shfl_xor(v, 1);
            v += __shfl_xor(v, 2);
            v += __shfl_xor(v, 4);
            v += __shfl_xor(v, 8);
            if (l16 == 0) atomicAdd(&S[gRow], v);
        }

    // col sums (transpose contribution)
#pragma unroll
    for (int ni = 0; ni < 8; ++ni) {
        float cv = 0.0f;
#pragma unroll
        for (int mi = 0; mi < 4; ++mi)
#pragma unroll
            for (int r = 0; r < 4; ++r) cv += acc[mi][ni][r];
        cv += __shfl_xor(cv, 16);
        cv += __shfl_xor(cv, 32);
        if (quad == 0) atomicAdd(&S[bCol + waveCol + ni * 16 + l16], cv);
    }

    // ---- last-block-done finalize ----
    // Drain OUR outstanding S-atomics before signalling. All S/cnt traffic
    // is device-scope atomics at the coherent point: cnt==grid-1 implies
    // every block's S-adds completed. No agent fence (R2 lesson: its L2
    // invalidate poisons co-resident GEMM blocks).
    asm volatile("s_waitcnt vmcnt(0) lgkmcnt(0)" ::: "memory");
    __shared__ int lastFlag;
    if (tid == 0) lastFlag = (atomicAdd(&cnt[1], 1) == (int)gridDim.x - 1);
    __syncthreads();
    if (!lastFlag) return;

    // Pipelined coherent reads (R3's serialized atomicAdd-RMW tail: +37us).
    float s0 = 0.0f, s1 = 0.0f, s2 = 0.0f, s3 = 0.0f;
    for (int i = tid; i < N; i += 1024) {      // N=8192: 8 iters x 4 loads
        const float a = agent_load(&S[i]);
        const float b = agent_load(&S[i + 256]);
        const float c = agent_load(&S[i + 512]);
        const float d = agent_load(&S[i + 768]);
        s0 += __logf(a); s1 += __logf(b); s2 += __logf(c); s3 += __logf(d);
    }
    float s = (s0 + s1) + (s2 + s3);

    // P written by norm_kernel (prior dispatch) -> plain loads are coherent.
    float pp = 0.0f;
    for (int i = tid; i < B; i += 1024)        // B=4096: 4 iters x 4 loads
        pp += P[i] + P[i + 256] + P[i + 512] + P[i + 768];

    for (int o = 32; o > 0; o >>= 1) {
        s += __shfl_down(s, o);
        pp += __shfl_down(pp, o);
    }
    __shared__ float redf[4][2];
    if (lane == 0) { redf[wave][0] = s; redf[wave][1] = pp; }
    __syncthreads();
    if (tid == 0) {
        const float sl = redf[0][0] + redf[1][0] + redf[2][0] + redf[3][0];
        const float ps = redf[0][1] + redf[1][1] + redf[2][1] + redf[3][1];
        out[0] = INV_T + sl / (float)N - ps * (2.0f * INV_T / (float)N);
    }
}

extern "C" void kernel_launch(void* const* d_in, const int* in_sizes, int n_in,
                              void* d_out, int out_size, void* d_ws, size_t ws_size,
                              hipStream_t stream) {
    const int D = 1024;
    const int B = in_sizes[0] / D;   // 4096
    const int N = 2 * B;             // 8192
    const int M2 = N / 256;          // 32 col-tiles
    const int ntiles = M2 * M2 + M2; // sum over tj of (2*tj+2) = 1056

    const float* f1 = (const float*)d_in[0];
    const float* f2 = (const float*)d_in[1];

    __hip_bfloat16* F = (__hip_bfloat16*)d_ws;  // N*D bf16 = 16 MB
    float* S = (float*)((char*)d_ws + (size_t)N * D * sizeof(__hip_bfloat16));
    float* P = S + N;                // B floats
    int* cnt = (int*)(P + B);        // [0]=unused, [1]=done ctr

    norm_kernel<<<dim3(B), dim3(256), 0, stream>>>(
        (const float4*)f1, (const float4*)f2, (ushort4*)F, S, P, cnt, B);
    sim_kernel<<<dim3(ntiles), dim3(256), 0, stream>>>(
        F, S, P, (float*)d_out, cnt, N, B, D);
}